// Round 4
// baseline (505.846 us; speedup 1.0000x reference)
//
#include <hip/hip_runtime.h>

// Conv x(32,64,128,128) * w(128,64,3,3) VALID + ReLU -> (32,128,126,126) flat.
// Implicit GEMM, bf16 MFMA 32x32x16, fp32 acc.
// R4: occupancy-focused. Block = 1 output row x 128 kout x 126 sp, 4 waves.
//   wave: kout half (wv&1) x sp half (wv>>1); per wave 64 kout x 64 sp
//   -> acc 64 f32/lane (was 128), LDS 3 x-rows = 48 KB (was 64).
//   Target: 3 blocks/CU (LDS) x 4 waves = 12 waves/CU = 3 waves/SIMD (vs 2).
//   Each ds_read_b128 B-frag still feeds 2 MFMAs (2 kout strips).
// Reads at sp 128/129 (tap shift) clamp to row 127; only touch store-masked
// output cols >=126 (MFMA is per-output-column). Swizzle pos=ch^((sp>>1)&7)
// measured 0 bank conflicts in R3.

#define OUT0_SIZE (32 * 128 * 15876)

typedef __attribute__((ext_vector_type(8))) short short8v;     // 8 bf16 (4 VGPRs)
typedef __attribute__((ext_vector_type(16))) float float16v;   // MFMA 32x32 C/D

static __device__ __forceinline__ unsigned bf16_rn(float f) {
  unsigned u = __float_as_uint(f);
  u += 0x7FFFu + ((u >> 16) & 1u);   // RNE; inputs are finite normals
  return u >> 16;
}
static __device__ __forceinline__ unsigned pk2(float a, float b) {
  return bf16_rn(a) | (bf16_rn(b) << 16);
}

// Prepass: w[kout][c][r][s] fp32 -> wt[tap=r*3+s][kout][c] bf16 (147 KB, L2-resident)
__global__ void repack_w(const float* __restrict__ w, unsigned short* __restrict__ wt) {
  int o = blockIdx.x * 256 + threadIdx.x;       // 9*128*64 = 73728
  if (o >= 9 * 128 * 64) return;
  int tap  = o >> 13;
  int rem  = o & 8191;
  int kout = rem >> 6;
  int c    = rem & 63;
  wt[o] = (unsigned short)bf16_rn(w[kout * 576 + c * 9 + tap]);
}

__global__ __launch_bounds__(256, 3) void conv3x3_relu_mfma(
    const float* __restrict__ x, const unsigned short* __restrict__ wt,
    float* __restrict__ out) {
  // Bs[xrow 0..2][sp 0..127][64 c] bf16, 16B-chunk swizzle pos = ch ^ ((sp>>1)&7).
  __shared__ __align__(16) unsigned short Bs[3][128][64];   // 48 KB -> 3 blocks/CU

  const int tid  = threadIdx.x;
  const int wv   = tid >> 6;
  const int lane = tid & 63;
  const int l31  = lane & 31;
  const int hb   = lane >> 5;

  // Bijective XCD swizzle for nwg=126 (126%8=6): xcd<6 get 16 rows, else 15.
  const int bx  = blockIdx.x;                // 0..125
  const int xcd = bx & 7;
  const int idx = bx >> 3;
  const int oh  = (xcd < 6 ? xcd * 16 : 96 + (xcd - 6) * 15) + idx;
  const int n   = blockIdx.y;

  const int kh = wv & 1;                     // kout half (64 kouts)
  const int sh = wv >> 1;                    // sp half (64 sp)

  // ---- stage 3 x rows (oh..oh+2), 64 c each, once; 2-deep load pipeline ----
  const int spp = lane;                      // sp pair (coalesced float2)
  const int c8b = tid >> 6;                  // 0..3 (+4 on odd half)
  const float* xp = x + n * 1048576 + oh * 128 + 2 * spp;

  float2 v[2][8];
#define ISSUE(it, buf)                                                         \
  {                                                                            \
    const int xrow_ = (it) >> 1, c8_ = c8b + ((it) & 1) * 4;                   \
    _Pragma("unroll")                                                          \
    for (int j = 0; j < 8; ++j)                                                \
      buf[j] = *(const float2*)(xp + xrow_ * 128 + (c8_ * 8 + j) * 16384);     \
  }
  ISSUE(0, v[0]);
#pragma unroll
  for (int it = 0; it < 6; ++it) {
    if (it < 5) ISSUE(it + 1, v[(it + 1) & 1]);
    float2* vv = v[it & 1];
    const int xrow = it >> 1;
    const int c8   = c8b + (it & 1) * 4;
    const int pos  = c8 ^ (spp & 7);
    uint4 lo = make_uint4(pk2(vv[0].x, vv[1].x), pk2(vv[2].x, vv[3].x),
                          pk2(vv[4].x, vv[5].x), pk2(vv[6].x, vv[7].x));
    uint4 hi = make_uint4(pk2(vv[0].y, vv[1].y), pk2(vv[2].y, vv[3].y),
                          pk2(vv[4].y, vv[5].y), pk2(vv[6].y, vv[7].y));
    *(uint4*)&Bs[xrow][2 * spp][pos * 8]     = lo;
    *(uint4*)&Bs[xrow][2 * spp + 1][pos * 8] = hi;
  }
#undef ISSUE
  __syncthreads();                            // the ONLY barrier

  // ---- accumulators: 64 kout x 64 sp per wave = 64 f32/lane ----
  float16v acc[2][2];
#pragma unroll
  for (int st = 0; st < 2; ++st)
#pragma unroll
    for (int nt = 0; nt < 2; ++nt)
#pragma unroll
      for (int rg = 0; rg < 16; ++rg)
        acc[st][nt][rg] = 0.f;

  // A: wt[tap][kout][c]; lane holds A[m=l31][k=hb*8..+7] of each 32x16 frag.
  const unsigned short* wtk = wt + (kh * 64 + l31) * 64 + hb * 8;

#pragma unroll
  for (int r = 0; r < 3; ++r) {
#pragma unroll
    for (int s = 0; s < 3; ++s) {
      const int tap = r * 3 + s;
      short8v a[2][4];
#pragma unroll
      for (int st = 0; st < 2; ++st)
#pragma unroll
        for (int ks = 0; ks < 4; ++ks)
          a[st][ks] = *(const short8v*)(wtk + tap * 8192 + st * 2048 + ks * 16);

      const unsigned short* Bp = &Bs[r][0][0];
#pragma unroll
      for (int nt = 0; nt < 2; ++nt) {
        const int sp  = sh * 64 + nt * 32 + l31 + s;
        const int spr = sp > 127 ? 127 : sp;   // clamp: only masked cols affected
        const int key = (spr >> 1) & 7;
#pragma unroll
        for (int ks = 0; ks < 4; ++ks) {
          const int pos = (ks * 2 + hb) ^ key;
          short8v b = *(const short8v*)(Bp + spr * 64 + pos * 8);
          acc[0][nt] = __builtin_amdgcn_mfma_f32_32x32x16_bf16(a[0][ks], b, acc[0][nt], 0, 0, 0);
          acc[1][nt] = __builtin_amdgcn_mfma_f32_32x32x16_bf16(a[1][ks], b, acc[1][nt], 0, 0, 0);
        }
      }
    }
  }

  // ---- epilogue: ReLU + store. C/D: col=l31 (sp), row=(rg&3)+8*(rg>>2)+4*hb ----
  const int ob = n * 128 * 15876 + oh * 126;
  const int kb = kh * 64 + 4 * hb;
#pragma unroll
  for (int st = 0; st < 2; ++st)
#pragma unroll
    for (int nt = 0; nt < 2; ++nt) {
      const int sp = sh * 64 + nt * 32 + l31;
      if (sp < 126) {
#pragma unroll
        for (int rg = 0; rg < 16; ++rg) {
          const int kout = kb + st * 32 + (rg & 3) + 8 * (rg >> 2);
          out[ob + kout * 15876 + sp] = fmaxf(acc[st][nt][rg], 0.0f);
        }
      }
    }
}

// Output 1: concat(a,b) last dim -> (1024, 2048), float4 copy.
__global__ void concat_kernel(const float* __restrict__ a,
                              const float* __restrict__ b,
                              float* __restrict__ o) {
  int i   = blockIdx.x * 256 + threadIdx.x;  // 524288 float4
  int row = i >> 9;
  int col = i & 511;
  const float4* src = (col < 256) ? (const float4*)a + (row << 8) + col
                                  : (const float4*)b + (row << 8) + (col - 256);
  ((float4*)o)[i] = *src;
}

extern "C" void kernel_launch(void* const* d_in, const int* in_sizes, int n_in,
                              void* d_out, int out_size, void* d_ws, size_t ws_size,
                              hipStream_t stream) {
  const float* x = (const float*)d_in[0];
  const float* w = (const float*)d_in[1];
  const float* a = (const float*)d_in[2];
  const float* b = (const float*)d_in[3];

  float* out0 = (float*)d_out;
  float* out1 = out0 + OUT0_SIZE;
  unsigned short* wt = (unsigned short*)d_ws;   // 147456 B

  repack_w<<<288, 256, 0, stream>>>(w, wt);
  dim3 grid(126, 32);
  conv3x3_relu_mfma<<<grid, 256, 0, stream>>>(x, wt, out0);
  concat_kernel<<<2048, 256, 0, stream>>>(a, b, out1);
}

// Round 5
// 432.691 us; speedup vs baseline: 1.1691x; 1.1691x over previous
//
#include <hip/hip_runtime.h>

// Conv x(32,64,128,128) * w(128,64,3,3) VALID + ReLU -> (32,128,126,126) flat.
// R5: line-buffer persistent blocks. Implicit GEMM, bf16 MFMA 32x32x16, fp32 acc.
// Block = 16 output rows x 128 kout x 126 sp, 8 waves (512 thr); grid 8x32 = 256
// blocks = exactly 1 per CU, single generation.
//   wave = kout-quad (wv&3, 32 kouts) x sp-half (wv>>2, 64 sp); acc 32 f32/lane.
//   A (weights): all 9 taps preloaded into 144 VGPR once per block -> zero weight
//   loads in the row loop; the loop's vmem queue holds only the 8 x-prefetch
//   loads (+ background stores), so the post-compute vmcnt wait is clean.
//   LDS: 4-slot ring of x rows (4 x 16 KB = 64 KB), slot = xrow & 3. Per step:
//   prefetch row oh+3 (issue) -> 9 taps MFMA from rows oh..oh+2 -> pack+write
//   slot (oh+3)&3 -> ONE barrier -> store row oh (fire-and-forget) -> next.
//   Slot being written holds row oh-1 (not read by step oh), and the barrier
//   gates step t+1's read of the new row AND step t+1's overwrite of row oh's
//   slot -> race-free with one barrier per row.
// Staging volume: 1 x-row per output row (R1:2, R3:2, R4:3 rows/orow).
// Swizzle pos = c8 ^ ((sp>>1)&7): measured 0 bank conflicts (R3/R4).
// Reads at sp 128/129 clamp to 127 -> only store-masked cols >=126 affected.

#define OUT0_SIZE (32 * 128 * 15876)

typedef __attribute__((ext_vector_type(8))) short short8v;     // 8 bf16 (4 VGPRs)
typedef __attribute__((ext_vector_type(16))) float float16v;   // MFMA 32x32 C/D

static __device__ __forceinline__ unsigned bf16_rn(float f) {
  unsigned u = __float_as_uint(f);
  u += 0x7FFFu + ((u >> 16) & 1u);   // RNE; inputs are finite normals
  return u >> 16;
}
static __device__ __forceinline__ unsigned pk2(float a, float b) {
  return bf16_rn(a) | (bf16_rn(b) << 16);
}

// Prepass: w[kout][c][r][s] fp32 -> wt[tap=r*3+s][kout][c] bf16 (147 KB, L2-resident)
__global__ void repack_w(const float* __restrict__ w, unsigned short* __restrict__ wt) {
  int o = blockIdx.x * 256 + threadIdx.x;       // 9*128*64 = 73728
  if (o >= 9 * 128 * 64) return;
  int tap  = o >> 13;
  int rem  = o & 8191;
  int kout = rem >> 6;
  int c    = rem & 63;
  wt[o] = (unsigned short)bf16_rn(w[kout * 576 + c * 9 + tap]);
}

__global__ __launch_bounds__(512, 2) void conv3x3_relu_mfma(
    const float* __restrict__ x, const unsigned short* __restrict__ wt,
    float* __restrict__ out) {
  // Ring: Bs[slot][sp 0..127][64 c] bf16, 16B-chunk swizzle pos = c8 ^ ((sp>>1)&7)
  __shared__ __align__(16) unsigned short Bs[4][128][64];   // 64 KB

  const int tid  = threadIdx.x;
  const int wv   = tid >> 6;                 // 0..7
  const int lane = tid & 63;
  const int l31  = lane & 31;
  const int hb   = lane >> 5;

  const int kq = wv & 3;                     // kout quad (32 kouts)
  const int sh = wv >> 2;                    // sp half (64 sp)

  const int chunk = blockIdx.x;              // 0..7
  const int n     = blockIdx.y;              // 0..31
  const int oh0   = chunk * 16;
  const int R     = (chunk == 7) ? 14 : 16;  // output rows this block

  // staging task: thread -> (sp-pair, channel-octet); 512 tasks = 1/thread/row
  const int spp   = tid & 63;
  const int c8    = tid >> 6;                // 0..7
  const int wposb = (c8 ^ (spp & 7)) * 8;    // swizzled 16B-chunk byte/2 offset
  const float* xp = x + n * 1048576 + 2 * spp;

  // ---- cold start: stage rows oh0..oh0+2 into ring ----
  for (int i = 0; i < 3; ++i) {
    const int h = oh0 + i;
    float2 v[8];
#pragma unroll
    for (int j = 0; j < 8; ++j)
      v[j] = *(const float2*)(xp + h * 128 + (c8 * 8 + j) * 16384);
    uint4 lo = make_uint4(pk2(v[0].x, v[1].x), pk2(v[2].x, v[3].x),
                          pk2(v[4].x, v[5].x), pk2(v[6].x, v[7].x));
    uint4 hi = make_uint4(pk2(v[0].y, v[1].y), pk2(v[2].y, v[3].y),
                          pk2(v[4].y, v[5].y), pk2(v[6].y, v[7].y));
    *(uint4*)&Bs[h & 3][2 * spp][wposb]     = lo;
    *(uint4*)&Bs[h & 3][2 * spp + 1][wposb] = hi;
  }

  // ---- A preload: 9 taps x 4 k-frags for this wave's 32-kout strip (144 VGPR) ----
  short8v a[9][4];
#pragma unroll
  for (int tap = 0; tap < 9; ++tap)
#pragma unroll
    for (int ks = 0; ks < 4; ++ks)
      a[tap][ks] = *(const short8v*)(wt + tap * 8192 +
                                     (kq * 32 + l31) * 64 + ks * 16 + hb * 8);

  __syncthreads();

  float16v acc[2];
#pragma unroll
  for (int nt = 0; nt < 2; ++nt)
#pragma unroll
    for (int rg = 0; rg < 16; ++rg)
      acc[nt][rg] = 0.f;

  for (int t = 0; t < R; ++t) {
    const int oh = oh0 + t;

    // issue prefetch of x row oh+3 (consumed after compute)
    float2 v[8];
    if (t < R - 1) {
#pragma unroll
      for (int j = 0; j < 8; ++j)
        v[j] = *(const float2*)(xp + (oh + 3) * 128 + (c8 * 8 + j) * 16384);
    }

    // ---- 9 taps from ring slots (oh..oh+2)&3 ----
#pragma unroll
    for (int r = 0; r < 3; ++r) {
      const unsigned short* Bp = &Bs[(oh + r) & 3][0][0];
#pragma unroll
      for (int s = 0; s < 3; ++s) {
#pragma unroll
        for (int nt = 0; nt < 2; ++nt) {
          const int sp  = sh * 64 + nt * 32 + l31 + s;
          const int spr = sp > 127 ? 127 : sp;   // clamp: only masked cols affected
          const int key = (spr >> 1) & 7;
#pragma unroll
          for (int ks = 0; ks < 4; ++ks) {
            const int pos = (ks * 2 + hb) ^ key;
            short8v b = *(const short8v*)(Bp + spr * 64 + pos * 8);
            acc[nt] = __builtin_amdgcn_mfma_f32_32x32x16_bf16(a[r * 3 + s][ks], b,
                                                              acc[nt], 0, 0, 0);
          }
        }
      }
    }

    // ---- pack + write prefetched row into slot (oh+3)&3 ----
    if (t < R - 1) {
      uint4 lo = make_uint4(pk2(v[0].x, v[1].x), pk2(v[2].x, v[3].x),
                            pk2(v[4].x, v[5].x), pk2(v[6].x, v[7].x));
      uint4 hi = make_uint4(pk2(v[0].y, v[1].y), pk2(v[2].y, v[3].y),
                            pk2(v[4].y, v[5].y), pk2(v[6].y, v[7].y));
      const int slot = (oh + 3) & 3;
      *(uint4*)&Bs[slot][2 * spp][wposb]     = lo;
      *(uint4*)&Bs[slot][2 * spp + 1][wposb] = hi;
    }
    __syncthreads();                          // one barrier per row

    // ---- epilogue row oh: ReLU + store (drains in background), re-zero acc ----
    const int ob = n * 128 * 15876 + oh * 126;
#pragma unroll
    for (int nt = 0; nt < 2; ++nt) {
      const int sp = sh * 64 + nt * 32 + l31;
      if (sp < 126) {
#pragma unroll
        for (int rg = 0; rg < 16; ++rg) {
          const int kout = kq * 32 + (rg & 3) + 8 * (rg >> 2) + 4 * hb;
          out[ob + kout * 15876 + sp] = fmaxf(acc[nt][rg], 0.0f);
        }
      }
#pragma unroll
      for (int rg = 0; rg < 16; ++rg) acc[nt][rg] = 0.f;
    }
  }
}

// Output 1: concat(a,b) last dim -> (1024, 2048), float4 copy.
__global__ void concat_kernel(const float* __restrict__ a,
                              const float* __restrict__ b,
                              float* __restrict__ o) {
  int i   = blockIdx.x * 256 + threadIdx.x;  // 524288 float4
  int row = i >> 9;
  int col = i & 511;
  const float4* src = (col < 256) ? (const float4*)a + (row << 8) + col
                                  : (const float4*)b + (row << 8) + (col - 256);
  ((float4*)o)[i] = *src;
}

extern "C" void kernel_launch(void* const* d_in, const int* in_sizes, int n_in,
                              void* d_out, int out_size, void* d_ws, size_t ws_size,
                              hipStream_t stream) {
  const float* x = (const float*)d_in[0];
  const float* w = (const float*)d_in[1];
  const float* a = (const float*)d_in[2];
  const float* b = (const float*)d_in[3];

  float* out0 = (float*)d_out;
  float* out1 = out0 + OUT0_SIZE;
  unsigned short* wt = (unsigned short*)d_ws;   // 147456 B

  repack_w<<<288, 256, 0, stream>>>(w, wt);
  dim3 grid(8, 32);
  conv3x3_relu_mfma<<<grid, 512, 0, stream>>>(x, wt, out0);
  concat_kernel<<<2048, 256, 0, stream>>>(a, b, out1);
}

// Round 6
// 422.926 us; speedup vs baseline: 1.1961x; 1.0231x over previous
//
#include <hip/hip_runtime.h>

// Conv x(32,64,128,128) * w(128,64,3,3) VALID + ReLU -> (32,128,126,126) flat.
// R6 = R5 (line-buffer persistent blocks, 1 block/CU, 4-slot LDS ring, all-tap
// A preload) + store decoupling:
//   per step: [barrier] -> issue prefetch loads (oldest vmem) -> 72 MFMA ->
//   epilogue stores (younger than loads -> pack's load-wait leaves them in
//   flight) -> pack+ds_write -> s_waitcnt lgkmcnt(0) + RAW s_barrier (no
//   vmcnt(0)!) -> next step. Output stores drain in background at HBM rate
//   instead of being hard-drained by __syncthreads' vmcnt(0) every step.
// Ring race-freedom unchanged from R5 (slot being written holds row oh-1,
// not read by step oh; barrier gates reads of the new row).
// Swizzle pos = c8 ^ ((sp>>1)&7): measured 0 bank conflicts (R3/R4).
// Reads at sp 128/129 clamp to 127 -> only store-masked cols >=126 affected.

#define OUT0_SIZE (32 * 128 * 15876)

typedef __attribute__((ext_vector_type(8))) short short8v;     // 8 bf16 (4 VGPRs)
typedef __attribute__((ext_vector_type(16))) float float16v;   // MFMA 32x32 C/D

static __device__ __forceinline__ unsigned bf16_rn(float f) {
  unsigned u = __float_as_uint(f);
  u += 0x7FFFu + ((u >> 16) & 1u);   // RNE; inputs are finite normals
  return u >> 16;
}
static __device__ __forceinline__ unsigned pk2(float a, float b) {
  return bf16_rn(a) | (bf16_rn(b) << 16);
}

// Prepass: w[kout][c][r][s] fp32 -> wt[tap=r*3+s][kout][c] bf16 (147 KB, L2-resident)
__global__ void repack_w(const float* __restrict__ w, unsigned short* __restrict__ wt) {
  int o = blockIdx.x * 256 + threadIdx.x;       // 9*128*64 = 73728
  if (o >= 9 * 128 * 64) return;
  int tap  = o >> 13;
  int rem  = o & 8191;
  int kout = rem >> 6;
  int c    = rem & 63;
  wt[o] = (unsigned short)bf16_rn(w[kout * 576 + c * 9 + tap]);
}

__global__ __launch_bounds__(512, 2) void conv3x3_relu_mfma(
    const float* __restrict__ x, const unsigned short* __restrict__ wt,
    float* __restrict__ out) {
  // Ring: Bs[slot][sp 0..127][64 c] bf16, 16B-chunk swizzle pos = c8 ^ ((sp>>1)&7)
  __shared__ __align__(16) unsigned short Bs[4][128][64];   // 64 KB

  const int tid  = threadIdx.x;
  const int wv   = tid >> 6;                 // 0..7
  const int lane = tid & 63;
  const int l31  = lane & 31;
  const int hb   = lane >> 5;

  const int kq = wv & 3;                     // kout quad (32 kouts)
  const int sh = wv >> 2;                    // sp half (64 sp)

  const int chunk = blockIdx.x;              // 0..7
  const int n     = blockIdx.y;              // 0..31
  const int oh0   = chunk * 16;
  const int R     = (chunk == 7) ? 14 : 16;  // output rows this block

  // staging task: thread -> (sp-pair, channel-octet); 512 tasks = 1/thread/row
  const int spp   = tid & 63;
  const int c8    = tid >> 6;                // 0..7
  const int wposb = (c8 ^ (spp & 7)) * 8;    // swizzled 16B-chunk offset (shorts)
  const float* xp = x + n * 1048576 + 2 * spp;

  // ---- cold start: stage rows oh0..oh0+2 into ring ----
  for (int i = 0; i < 3; ++i) {
    const int h = oh0 + i;
    float2 v[8];
#pragma unroll
    for (int j = 0; j < 8; ++j)
      v[j] = *(const float2*)(xp + h * 128 + (c8 * 8 + j) * 16384);
    uint4 lo = make_uint4(pk2(v[0].x, v[1].x), pk2(v[2].x, v[3].x),
                          pk2(v[4].x, v[5].x), pk2(v[6].x, v[7].x));
    uint4 hi = make_uint4(pk2(v[0].y, v[1].y), pk2(v[2].y, v[3].y),
                          pk2(v[4].y, v[5].y), pk2(v[6].y, v[7].y));
    *(uint4*)&Bs[h & 3][2 * spp][wposb]     = lo;
    *(uint4*)&Bs[h & 3][2 * spp + 1][wposb] = hi;
  }

  // ---- A preload: 9 taps x 4 k-frags for this wave's 32-kout strip (144 VGPR) ----
  short8v a[9][4];
#pragma unroll
  for (int tap = 0; tap < 9; ++tap)
#pragma unroll
    for (int ks = 0; ks < 4; ++ks)
      a[tap][ks] = *(const short8v*)(wt + tap * 8192 +
                                     (kq * 32 + l31) * 64 + ks * 16 + hb * 8);

  __syncthreads();                           // cold-start barrier (full drain ok)

  float16v acc[2];
#pragma unroll
  for (int nt = 0; nt < 2; ++nt)
#pragma unroll
    for (int rg = 0; rg < 16; ++rg)
      acc[nt][rg] = 0.f;

  for (int t = 0; t < R; ++t) {
    const int oh = oh0 + t;

    // 1) issue prefetch of x row oh+3 FIRST (oldest vmem ops of this step)
    float2 v[8];
    if (t < R - 1) {
#pragma unroll
      for (int j = 0; j < 8; ++j)
        v[j] = *(const float2*)(xp + (oh + 3) * 128 + (c8 * 8 + j) * 16384);
    }

    // 2) 9 taps from ring slots (oh..oh+2)&3
#pragma unroll
    for (int r = 0; r < 3; ++r) {
      const unsigned short* Bp = &Bs[(oh + r) & 3][0][0];
#pragma unroll
      for (int s = 0; s < 3; ++s) {
#pragma unroll
        for (int nt = 0; nt < 2; ++nt) {
          const int sp  = sh * 64 + nt * 32 + l31 + s;
          const int spr = sp > 127 ? 127 : sp;   // clamp: only masked cols affected
          const int key = (spr >> 1) & 7;
#pragma unroll
          for (int ks = 0; ks < 4; ++ks) {
            const int pos = (ks * 2 + hb) ^ key;
            short8v b = *(const short8v*)(Bp + spr * 64 + pos * 8);
            acc[nt] = __builtin_amdgcn_mfma_f32_32x32x16_bf16(a[r * 3 + s][ks], b,
                                                              acc[nt], 0, 0, 0);
          }
        }
      }
    }

    // 3) epilogue row oh: ReLU + store (YOUNGER than the prefetch loads ->
    //    pack's load-wait below leaves these in flight), re-zero acc
    {
      const int ob = n * 128 * 15876 + oh * 126;
#pragma unroll
      for (int nt = 0; nt < 2; ++nt) {
        const int sp = sh * 64 + nt * 32 + l31;
        if (sp < 126) {
#pragma unroll
          for (int rg = 0; rg < 16; ++rg) {
            const int kout = kq * 32 + (rg & 3) + 8 * (rg >> 2) + 4 * hb;
            out[ob + kout * 15876 + sp] = fmaxf(acc[nt][rg], 0.0f);
          }
        }
#pragma unroll
        for (int rg = 0; rg < 16; ++rg) acc[nt][rg] = 0.f;
      }
    }

    // 4) pack prefetched row into slot (oh+3)&3, then lgkm-only barrier
    if (t < R - 1) {
      uint4 lo = make_uint4(pk2(v[0].x, v[1].x), pk2(v[2].x, v[3].x),
                            pk2(v[4].x, v[5].x), pk2(v[6].x, v[7].x));
      uint4 hi = make_uint4(pk2(v[0].y, v[1].y), pk2(v[2].y, v[3].y),
                            pk2(v[4].y, v[5].y), pk2(v[6].y, v[7].y));
      const int slot = (oh + 3) & 3;
      *(uint4*)&Bs[slot][2 * spp][wposb]     = lo;
      *(uint4*)&Bs[slot][2 * spp + 1][wposb] = hi;
      // ds_writes visible to all waves, WITHOUT draining the output stores:
      asm volatile("s_waitcnt lgkmcnt(0)" ::: "memory");
      __builtin_amdgcn_s_barrier();
      __builtin_amdgcn_sched_barrier(0);     // keep next step's ds_reads below
    }
  }
}

// Output 1: concat(a,b) last dim -> (1024, 2048), float4 copy.
__global__ void concat_kernel(const float* __restrict__ a,
                              const float* __restrict__ b,
                              float* __restrict__ o) {
  int i   = blockIdx.x * 256 + threadIdx.x;  // 524288 float4
  int row = i >> 9;
  int col = i & 511;
  const float4* src = (col < 256) ? (const float4*)a + (row << 8) + col
                                  : (const float4*)b + (row << 8) + (col - 256);
  ((float4*)o)[i] = *src;
}

extern "C" void kernel_launch(void* const* d_in, const int* in_sizes, int n_in,
                              void* d_out, int out_size, void* d_ws, size_t ws_size,
                              hipStream_t stream) {
  const float* x = (const float*)d_in[0];
  const float* w = (const float*)d_in[1];
  const float* a = (const float*)d_in[2];
  const float* b = (const float*)d_in[3];

  float* out0 = (float*)d_out;
  float* out1 = out0 + OUT0_SIZE;
  unsigned short* wt = (unsigned short*)d_ws;   // 147456 B

  repack_w<<<288, 256, 0, stream>>>(w, wt);
  dim3 grid(8, 32);
  conv3x3_relu_mfma<<<grid, 512, 0, stream>>>(x, wt, out0);
  concat_kernel<<<2048, 256, 0, stream>>>(a, b, out1);
}